// Round 21
// baseline (326.305 us; speedup 1.0000x reference)
//
#include <hip/hip_runtime.h>
#include <hip/hip_bf16.h>
#include <stdint.h>

#define T_TOK 2048
#define DIM   1024
#define HDIM  2048
#define NE    8
#define ROWS_PAD 4224   // 4096 routed rows + 128 pad for tile overrun
#define TS64 80         // max live (expert,mtile64) pairs: 64 + 7 padded

typedef __attribute__((ext_vector_type(8))) short bf16x8;
typedef __attribute__((ext_vector_type(8))) unsigned short u16x8;
typedef __attribute__((ext_vector_type(4))) float f32x4;
typedef __attribute__((ext_vector_type(4))) unsigned int u32x4;

__device__ __forceinline__ unsigned short f2bf(float f) {
    union { __hip_bfloat16 h; unsigned short u; } cv;
    cv.h = __float2bfloat16(f);
    return cv.u;
}
__device__ __forceinline__ unsigned int f2bf2(float lo, float hi) {
    union { __hip_bfloat162 h; unsigned int u; } cv;
    cv.h = __float22bfloat162_rn(make_float2(lo, hi));
    return cv.u;
}
__device__ __forceinline__ float bf2f(unsigned short b) {
    union { unsigned int u; float f; } v; v.u = ((unsigned int)b) << 16;
    return v.f;
}

__device__ __forceinline__ void gload16(const void* g, void* l) {
    __builtin_amdgcn_global_load_lds(
        (const __attribute__((address_space(1))) void*)g,
        (__attribute__((address_space(3))) void*)l, 16, 0, 0);
}

// ---------------- router: logits = x @ rw, top-2 softmax, counts
__global__ void router_kernel(const float* __restrict__ x, const float* __restrict__ rw,
                              int* __restrict__ counts, int* __restrict__ top_idx,
                              float* __restrict__ top_w) {
    int wid = (blockIdx.x * blockDim.x + threadIdx.x) >> 6;
    int lane = threadIdx.x & 63;
    if (wid >= T_TOK) return;
    float acc[NE];
#pragma unroll
    for (int e = 0; e < NE; ++e) acc[e] = 0.f;
    const float* xr = x + (size_t)wid * DIM;
    for (int i = lane; i < DIM; i += 64) {
        float xv = xr[i];
        const float* wr = rw + (size_t)i * NE;
#pragma unroll
        for (int e = 0; e < NE; ++e) acc[e] += xv * wr[e];
    }
#pragma unroll
    for (int off = 32; off; off >>= 1) {
#pragma unroll
        for (int e = 0; e < NE; ++e) acc[e] += __shfl_xor(acc[e], off, 64);
    }
    if (lane == 0) {
        float v0 = -1e30f, v1 = -1e30f; int i0 = 0, i1 = 0;
#pragma unroll
        for (int e = 0; e < NE; ++e) {
            float v = acc[e];
            if (v > v0) { v1 = v0; i1 = i0; v0 = v; i0 = e; }
            else if (v > v1) { v1 = v; i1 = e; }
        }
        float e1 = __expf(v1 - v0);
        float s = 1.f + e1;
        top_idx[wid * 2]     = i0;
        top_idx[wid * 2 + 1] = i1;
        top_w[wid * 2]     = 1.f / s;
        top_w[wid * 2 + 1] = e1 / s;
        atomicAdd(&counts[i0], 1);
        atomicAdd(&counts[i1], 1);
    }
}

// ---------------- scan + compact 64-row tile list (holes only at the tail)
__global__ void scan_kernel(const int* __restrict__ counts, int* __restrict__ offsets,
                            int* __restrict__ cursors,
                            int* __restrict__ tl_e, int* __restrict__ tl_m) {
    if (threadIdx.x == 0) {
        int run = 0;
        for (int e = 0; e < NE; ++e) { offsets[e] = run; cursors[e] = run; run += counts[e]; }
        int n = 0;
        for (int e = 0; e < NE; ++e) {
            int mt = (counts[e] + 63) >> 6;
            for (int m = 0; m < mt && n < TS64; ++m) { tl_e[n] = e; tl_m[n] = m; ++n; }
        }
        for (; n < TS64; ++n) tl_e[n] = -1;
    }
}

// ---------------- gather: pack each token's row (bf16) into its 2 experts' segments
__global__ void gather_kernel(const float* __restrict__ x, const int* __restrict__ top_idx,
                              const float* __restrict__ top_w, int* __restrict__ cursors,
                              int* __restrict__ row_tok, float* __restrict__ row_w,
                              unsigned short* __restrict__ Abuf) {
    int t = blockIdx.x;
    __shared__ int pos[2];
    if (threadIdx.x < 2) {
        int k = threadIdx.x;
        int e = top_idx[t * 2 + k];
        int p = atomicAdd(&cursors[e], 1);
        pos[k] = p;
        row_tok[p] = t;
        row_w[p] = top_w[t * 2 + k];
    }
    __syncthreads();
    const float4* xr = (const float4*)(x + (size_t)t * DIM);
    float4 v = xr[threadIdx.x];
    uint2 b; b.x = f2bf2(v.x, v.y); b.y = f2bf2(v.z, v.w);
    uint2* A4 = (uint2*)Abuf;
    A4[(size_t)pos[0] * (DIM / 4) + threadIdx.x] = b;
    A4[(size_t)pos[1] * (DIM / 4) + threadIdx.x] = b;
}

// ---------------- GEMM1 small-block: z=0 -> Hs = silu(A @ Wg^T); z=1 -> Hu = A @ Wu^T
// 128 threads (2 waves = 2 n-halves), BM=64, BN=64, BK=64; LDS 32KB -> 5 blocks/CU.
// B staging = R17's MEASURED-ZERO-CONFLICT pattern: thread owns col bn=tid&63,
// wave h loads k-chunks h*4..h*4+3 (scalar strided fp32, 256B/instr along n),
// XOR write slot = c ^ (bn&7). A via global_load_lds. 2-phase double-buffer.
__global__ __launch_bounds__(128, 3)
void gemm1s_kernel(const unsigned short* __restrict__ Abuf,
                   const float* __restrict__ gw,
                   const float* __restrict__ uw,
                   unsigned short* __restrict__ Hs,
                   unsigned short* __restrict__ Hu,
                   const int* __restrict__ offsets, const int* __restrict__ counts,
                   const int* __restrict__ tl_e, const int* __restrict__ tl_m) {
    const int slot = blockIdx.y;
    const int e = tl_e[slot];
    if (e < 0) return;
    const int mtile = tl_m[slot];
    const int cnt = counts[e];
    const int n0 = blockIdx.x * 64;
    const int row0 = offsets[e] + mtile * 64;
    const int zu = blockIdx.z;          // 0 = gate(-> silu), 1 = up
    const float* W = zu ? uw : gw;
    unsigned short* Hx = zu ? Hu : Hs;

    __shared__ unsigned short AsB[2][64 * 64];   // 16 KB
    __shared__ unsigned short Bb[2][64 * 64];    // 16 KB

    const int tid = threadIdx.x;
    const int lane = tid & 63;
    const int wn = tid >> 6;            // wave = n-half (0,1)

    f32x4 acc[4][2];
#pragma unroll
    for (int i = 0; i < 4; ++i)
#pragma unroll
        for (int j = 0; j < 2; ++j) acc[i][j] = (f32x4){0.f, 0.f, 0.f, 0.f};

    const unsigned short* Aab = Abuf + (size_t)row0 * DIM;
    auto stageA = [&](int buf, int kt) {
#pragma unroll
        for (int i = 0; i < 4; ++i) {
            int idx = i * 128 + tid;            // 0..511 = 64 rows x 8 chunks
            int row = idx >> 3, sc = idx & 7;
            int csrc = sc ^ (row & 7);
            gload16(Aab + (size_t)row * DIM + kt + csrc * 8,
                    &AsB[buf][idx * 8]);
        }
    };

    // B (R17 pattern): thread owns col bn; wave h covers chunks h*4 + cc
    const int bn = tid & 63;
    const int bh = tid >> 6;
    const float* Bgb = W + (size_t)e * DIM * HDIM + n0 + bn;

    float bl[4][8];
    auto bload = [&](int kt) {
#pragma unroll
        for (int cc = 0; cc < 4; ++cc) {
            int c = bh * 4 + cc;
            const float* gs = Bgb + (size_t)(kt + c * 8) * HDIM;
#pragma unroll
            for (int jj = 0; jj < 8; ++jj)
                bl[cc][jj] = gs[(size_t)jj * HDIM];
        }
    };
    auto bwrite = [&](int buf) {
#pragma unroll
        for (int cc = 0; cc < 4; ++cc) {
            int c = bh * 4 + cc;
            int la = bn * 64 + ((c ^ (bn & 7)) * 8);
            u32x4 v;
#pragma unroll
            for (int p = 0; p < 4; ++p)
                v[p] = f2bf2(bl[cc][2 * p], bl[cc][2 * p + 1]);
            *(u32x4*)&Bb[buf][la] = v;
        }
    };

    const int rsel = lane & 15;
    const int csrcf = lane >> 4;        // fragment k-chunk (0..3)

    stageA(0, 0);
    bload(0);
    bwrite(0);
    int cur = 0;
    for (int kt = 0; kt < DIM; kt += 64) {
        __syncthreads();                // buf[cur] ready
        const bool pre = (kt + 64 < DIM);
        if (pre) { stageA(cur ^ 1, kt + 64); bload(kt + 64); }   // issue early
        const unsigned short* Ac = AsB[cur];
        const unsigned short* Bc = Bb[cur];
#pragma unroll
        for (int kk = 0; kk < 2; ++kk) {
            bf16x8 af[4], bb[2];
#pragma unroll
            for (int i = 0; i < 4; ++i) {
                int ra = i * 16 + rsel;
                af[i] = *(const bf16x8*)&Ac[ra * 64 + ((kk * 4 + csrcf) ^ (ra & 7)) * 8];
            }
#pragma unroll
            for (int j = 0; j < 2; ++j) {
                int rb = wn * 32 + j * 16 + rsel;
                bb[j] = *(const bf16x8*)&Bc[rb * 64 + ((kk * 4 + csrcf) ^ (rb & 7)) * 8];
            }
#pragma unroll
            for (int i = 0; i < 4; ++i)
#pragma unroll
                for (int j = 0; j < 2; ++j)
                    acc[i][j] = __builtin_amdgcn_mfma_f32_16x16x32_bf16(af[i], bb[j], acc[i][j], 0, 0, 0);
        }
        if (pre) bwrite(cur ^ 1);       // write late
        cur ^= 1;
    }

    const int c = lane & 15, rbase = (lane >> 4) * 4;
    const int obase = offsets[e];
#pragma unroll
    for (int i = 0; i < 4; ++i) {
#pragma unroll
        for (int r = 0; r < 4; ++r) {
            int lrow = mtile * 64 + i * 16 + rbase + r;
            if (lrow < cnt) {
                size_t orow = (size_t)(obase + lrow);
#pragma unroll
                for (int j = 0; j < 2; ++j) {
                    float v = acc[i][j][r];
                    if (!zu) v = v / (1.f + __expf(-v));   // silu on gate path
                    Hx[orow * HDIM + n0 + wn * 32 + j * 16 + c] = f2bf(v);
                }
            }
        }
    }
}

// ---------------- GEMM2 small-block: y[tok] += w * ((Hs*Hu) @ Wd^T)
// 128 threads, BM=64, BN=64, BK=64, full K (32 steps). A = in-register Hs*Hu
// product -> audited-conflict-free swizzled writes; B = R17 pattern on fp32 dw.
__global__ __launch_bounds__(128, 3)
void gemm2s_kernel(const unsigned short* __restrict__ Hs,
                   const unsigned short* __restrict__ Hu,
                   const float* __restrict__ dw,
                   float* __restrict__ y,
                   const int* __restrict__ offsets, const int* __restrict__ counts,
                   const int* __restrict__ row_tok, const float* __restrict__ row_w,
                   const int* __restrict__ tl_e, const int* __restrict__ tl_m) {
    const int slot = blockIdx.y;
    const int e = tl_e[slot];
    if (e < 0) return;
    const int mtile = tl_m[slot];
    const int cnt = counts[e];
    const int n0 = blockIdx.x * 64;
    const int row0 = offsets[e] + mtile * 64;

    __shared__ unsigned short As[2][64 * 64];   // 16 KB
    __shared__ unsigned short Bs[2][64 * 64];   // 16 KB

    const int tid = threadIdx.x;
    const int lane = tid & 63;
    const int wn = tid >> 6;

    f32x4 acc[4][2];
#pragma unroll
    for (int i = 0; i < 4; ++i)
#pragma unroll
        for (int j = 0; j < 2; ++j) acc[i][j] = (f32x4){0.f, 0.f, 0.f, 0.f};

    // A: thread (row = tid>>1, chunk-half = (tid&1)*4): 4 u16x8 pairs -> product
    const int ar = tid >> 1;
    const int ah = (tid & 1) * 4;
    const unsigned short* Asb = Hs + (size_t)(row0 + ar) * HDIM;
    const unsigned short* Aub = Hu + (size_t)(row0 + ar) * HDIM;

    u16x8 as_[4], au_[4];
    auto aload = [&](int kt) {
#pragma unroll
        for (int cc = 0; cc < 4; ++cc) {
            size_t go = (size_t)kt + (ah + cc) * 8;
            as_[cc] = *(const u16x8*)&Asb[go];
            au_[cc] = *(const u16x8*)&Aub[go];
        }
    };
    auto awrite = [&](int buf) {
#pragma unroll
        for (int cc = 0; cc < 4; ++cc) {
            int ch = ah + cc;
            u32x4 v;
#pragma unroll
            for (int p = 0; p < 4; ++p) {
                float h0 = bf2f(as_[cc][2 * p])     * bf2f(au_[cc][2 * p]);
                float h1 = bf2f(as_[cc][2 * p + 1]) * bf2f(au_[cc][2 * p + 1]);
                v[p] = f2bf2(h0, h1);
            }
            *(u32x4*)&As[buf][ar * 64 + ((ch ^ (ar & 7)) * 8)] = v;
        }
    };

    // B (R17 pattern): thread owns col bn; wave h covers chunks h*4 + cc
    const int bn = tid & 63;
    const int bh = tid >> 6;
    const float* Bbb = dw + (size_t)e * HDIM * DIM + n0 + bn;

    float bl[4][8];
    auto bload = [&](int kt) {
#pragma unroll
        for (int cc = 0; cc < 4; ++cc) {
            int c = bh * 4 + cc;
            const float* bs = Bbb + (size_t)(kt + c * 8) * DIM;
#pragma unroll
            for (int jj = 0; jj < 8; ++jj)
                bl[cc][jj] = bs[(size_t)jj * DIM];
        }
    };
    auto bwrite = [&](int buf) {
#pragma unroll
        for (int cc = 0; cc < 4; ++cc) {
            int c = bh * 4 + cc;
            int la = bn * 64 + ((c ^ (bn & 7)) * 8);
            u32x4 v;
#pragma unroll
            for (int p = 0; p < 4; ++p)
                v[p] = f2bf2(bl[cc][2 * p], bl[cc][2 * p + 1]);
            *(u32x4*)&Bs[buf][la] = v;
        }
    };

    const int rsel = lane & 15;
    const int csrcf = lane >> 4;

    aload(0);
    bload(0);
    awrite(0);
    bwrite(0);
    int cur = 0;
    for (int kt = 0; kt < HDIM; kt += 64) {
        __syncthreads();
        const bool pre = (kt + 64 < HDIM);
        if (pre) { aload(kt + 64); bload(kt + 64); }
        const unsigned short* Ac = As[cur];
        const unsigned short* Bc = Bs[cur];
#pragma unroll
        for (int kk = 0; kk < 2; ++kk) {
            bf16x8 af[4], bf[2];
#pragma unroll
            for (int i = 0; i < 4; ++i) {
                int ra = i * 16 + rsel;
                af[i] = *(const bf16x8*)&Ac[ra * 64 + ((kk * 4 + csrcf) ^ (ra & 7)) * 8];
            }
#pragma unroll
            for (int j = 0; j < 2; ++j) {
                int rb = wn * 32 + j * 16 + rsel;
                bf[j] = *(const bf16x8*)&Bc[rb * 64 + ((kk * 4 + csrcf) ^ (rb & 7)) * 8];
            }
#pragma unroll
            for (int i = 0; i < 4; ++i)
#pragma unroll
                for (int j = 0; j < 2; ++j)
                    acc[i][j] = __builtin_amdgcn_mfma_f32_16x16x32_bf16(af[i], bf[j], acc[i][j], 0, 0, 0);
        }
        if (pre) { awrite(cur ^ 1); bwrite(cur ^ 1); }
        cur ^= 1;
    }

    const int c = lane & 15, rbase = (lane >> 4) * 4;
    const int obase = offsets[e];
#pragma unroll
    for (int i = 0; i < 4; ++i) {
#pragma unroll
        for (int r = 0; r < 4; ++r) {
            int lrow = mtile * 64 + i * 16 + rbase + r;
            if (lrow < cnt) {
                int grow = obase + lrow;
                int tok = row_tok[grow];
                float w = row_w[grow];
#pragma unroll
                for (int j = 0; j < 2; ++j) {
                    atomicAdd(&y[(size_t)tok * DIM + n0 + wn * 32 + j * 16 + c], w * acc[i][j][r]);
                }
            }
        }
    }
}

extern "C" void kernel_launch(void* const* d_in, const int* in_sizes, int n_in,
                              void* d_out, int out_size, void* d_ws, size_t ws_size,
                              hipStream_t stream) {
    const float* x  = (const float*)d_in[0];
    const float* rw = (const float*)d_in[1];
    const float* gw = (const float*)d_in[2];
    const float* uw = (const float*)d_in[3];
    const float* dw = (const float*)d_in[4];
    float* y = (float*)d_out;

    char* ws = (char*)d_ws;
    int*   counts  = (int*)(ws + 0);
    int*   cursors = (int*)(ws + 32);
    int*   offsets = (int*)(ws + 64);
    int*   top_idx = (int*)(ws + 128);
    float* top_w   = (float*)(ws + 128 + 16384);
    int*   row_tok = (int*)(ws + 128 + 32768);
    float* row_w   = (float*)(ws + 128 + 32768 + 16896);
    int*   tl_e    = (int*)(ws + 128 + 32768 + 2 * 16896);
    int*   tl_m    = (int*)(ws + 128 + 32768 + 2 * 16896 + 512);
    size_t off = 128 + 32768 + 2 * 16896 + 1024;
    off = (off + 255) & ~(size_t)255;
    unsigned short* Abuf = (unsigned short*)(ws + off); off += (size_t)ROWS_PAD * DIM * 2;
    unsigned short* Hs   = (unsigned short*)(ws + off); off += (size_t)ROWS_PAD * HDIM * 2;
    unsigned short* Hu   = (unsigned short*)(ws + off); off += (size_t)ROWS_PAD * HDIM * 2;
    if (ws_size < off) return;  // workspace too small: fail loudly (zero output)

    hipMemsetAsync(counts, 0, 32, stream);
    hipMemsetAsync(d_out, 0, (size_t)out_size * 4, stream);

    router_kernel<<<T_TOK / 4, 256, 0, stream>>>(x, rw, counts, top_idx, top_w);
    scan_kernel<<<1, 64, 0, stream>>>(counts, offsets, cursors, tl_e, tl_m);
    gather_kernel<<<T_TOK, 256, 0, stream>>>(x, top_idx, top_w, cursors, row_tok, row_w, Abuf);

    gemm1s_kernel<<<dim3(HDIM / 64, TS64, 2), 128, 0, stream>>>(Abuf, gw, uw, Hs, Hu,
                                                                offsets, counts, tl_e, tl_m);
    gemm2s_kernel<<<dim3(DIM / 64, TS64), 128, 0, stream>>>(Hs, Hu, dw, y, offsets, counts,
                                                            row_tok, row_w, tl_e, tl_m);
}

// Round 22
// 296.163 us; speedup vs baseline: 1.1018x; 1.1018x over previous
//
#include <hip/hip_runtime.h>
#include <hip/hip_bf16.h>
#include <stdint.h>

#define T_TOK 2048
#define DIM   1024
#define HDIM  2048
#define NE    8
#define ROWS_PAD 4224   // 4096 routed rows + 128 pad for tile overrun
#define TSLOTS 40       // max live (expert,mtile128) pairs: 32 + 7 = 39

typedef __attribute__((ext_vector_type(8))) short bf16x8;
typedef __attribute__((ext_vector_type(8))) unsigned short u16x8;
typedef __attribute__((ext_vector_type(4))) float f32x4;
typedef __attribute__((ext_vector_type(4))) unsigned int u32x4;

__device__ __forceinline__ unsigned short f2bf(float f) {
    union { __hip_bfloat16 h; unsigned short u; } cv;
    cv.h = __float2bfloat16(f);
    return cv.u;
}
__device__ __forceinline__ unsigned int f2bf2(float lo, float hi) {
    union { __hip_bfloat162 h; unsigned int u; } cv;
    cv.h = __float22bfloat162_rn(make_float2(lo, hi));
    return cv.u;
}
__device__ __forceinline__ float bf2f(unsigned short b) {
    union { unsigned int u; float f; } v; v.u = ((unsigned int)b) << 16;
    return v.f;
}

__device__ __forceinline__ void gload16(const void* g, void* l) {
    __builtin_amdgcn_global_load_lds(
        (const __attribute__((address_space(1))) void*)g,
        (__attribute__((address_space(3))) void*)l, 16, 0, 0);
}

// bijective XCD-chunk swizzle (m157/m204): physical bid -> logical id such that
// logical ids are contiguous per XCD chunk. Requires nwg % 8 == 0.
__device__ __forceinline__ int xcd_logical(int bid, int nwg) {
    int cpx = nwg >> 3;
    return (bid & 7) * cpx + (bid >> 3);
}

// ---------------- router: logits = x @ rw, top-2 softmax, counts
__global__ void router_kernel(const float* __restrict__ x, const float* __restrict__ rw,
                              int* __restrict__ counts, int* __restrict__ top_idx,
                              float* __restrict__ top_w) {
    int wid = (blockIdx.x * blockDim.x + threadIdx.x) >> 6;
    int lane = threadIdx.x & 63;
    if (wid >= T_TOK) return;
    float acc[NE];
#pragma unroll
    for (int e = 0; e < NE; ++e) acc[e] = 0.f;
    const float* xr = x + (size_t)wid * DIM;
    for (int i = lane; i < DIM; i += 64) {
        float xv = xr[i];
        const float* wr = rw + (size_t)i * NE;
#pragma unroll
        for (int e = 0; e < NE; ++e) acc[e] += xv * wr[e];
    }
#pragma unroll
    for (int off = 32; off; off >>= 1) {
#pragma unroll
        for (int e = 0; e < NE; ++e) acc[e] += __shfl_xor(acc[e], off, 64);
    }
    if (lane == 0) {
        float v0 = -1e30f, v1 = -1e30f; int i0 = 0, i1 = 0;
#pragma unroll
        for (int e = 0; e < NE; ++e) {
            float v = acc[e];
            if (v > v0) { v1 = v0; i1 = i0; v0 = v; i0 = e; }
            else if (v > v1) { v1 = v; i1 = e; }
        }
        float e1 = __expf(v1 - v0);
        float s = 1.f + e1;
        top_idx[wid * 2]     = i0;
        top_idx[wid * 2 + 1] = i1;
        top_w[wid * 2]     = 1.f / s;
        top_w[wid * 2 + 1] = e1 / s;
        atomicAdd(&counts[i0], 1);
        atomicAdd(&counts[i1], 1);
    }
}

// ---------------- scan + compact tile list (holes only at the tail)
__global__ void scan_kernel(const int* __restrict__ counts, int* __restrict__ offsets,
                            int* __restrict__ cursors,
                            int* __restrict__ tl_e, int* __restrict__ tl_m) {
    if (threadIdx.x == 0) {
        int run = 0;
        for (int e = 0; e < NE; ++e) { offsets[e] = run; cursors[e] = run; run += counts[e]; }
        int n = 0;
        for (int e = 0; e < NE; ++e) {
            int mt = (counts[e] + 127) >> 7;
            for (int m = 0; m < mt && n < 64; ++m) { tl_e[n] = e; tl_m[n] = m; ++n; }
        }
        for (; n < 64; ++n) tl_e[n] = -1;
    }
}

// ---------------- gather: pack each token's row (bf16) into its 2 experts' segments
__global__ void gather_kernel(const float* __restrict__ x, const int* __restrict__ top_idx,
                              const float* __restrict__ top_w, int* __restrict__ cursors,
                              int* __restrict__ row_tok, float* __restrict__ row_w,
                              unsigned short* __restrict__ Abuf) {
    int t = blockIdx.x;
    __shared__ int pos[2];
    if (threadIdx.x < 2) {
        int k = threadIdx.x;
        int e = top_idx[t * 2 + k];
        int p = atomicAdd(&cursors[e], 1);
        pos[k] = p;
        row_tok[p] = t;
        row_w[p] = top_w[t * 2 + k];
    }
    __syncthreads();
    const float4* xr = (const float4*)(x + (size_t)t * DIM);
    float4 v = xr[threadIdx.x];
    uint2 b; b.x = f2bf2(v.x, v.y); b.y = f2bf2(v.z, v.w);
    uint2* A4 = (uint2*)Abuf;
    A4[(size_t)pos[0] * (DIM / 4) + threadIdx.x] = b;
    A4[(size_t)pos[1] * (DIM / 4) + threadIdx.x] = b;
}

// ---------------- GEMM1 split: z=0 -> Hs = silu(A @ Wg^T); z=1 -> Hu = A @ Wu^T
// (R18-proven internals.)  BM=128, BN=64, BK=64; 4 waves = 2(m)x2(n), acc[4][2];
// LDS 48KB -> 3/CU. 1D grid, XCD-chunked, B-panel-major logical order:
// logical = (z*32 + n0idx)*TSLOTS + slot  (panel sharers adjacent -> same XCD L2).
__global__ __launch_bounds__(256, 3)
void gemm1s_kernel(const unsigned short* __restrict__ Abuf,
                   const float* __restrict__ gw,
                   const float* __restrict__ uw,
                   unsigned short* __restrict__ Hs,
                   unsigned short* __restrict__ Hu,
                   const int* __restrict__ offsets, const int* __restrict__ counts,
                   const int* __restrict__ tl_e, const int* __restrict__ tl_m) {
    const int log = xcd_logical(blockIdx.x, 64 * TSLOTS);
    const int slot = log % TSLOTS;
    const int nz = log / TSLOTS;          // 0..63
    const int n0 = (nz & 31) * 64;
    const int zu = nz >> 5;               // 0 = gate(-> silu), 1 = up
    const int e = tl_e[slot];
    if (e < 0) return;
    const int mtile = tl_m[slot];
    const int cnt = counts[e];
    const int row0 = offsets[e] + mtile * 128;
    const float* W = zu ? uw : gw;
    unsigned short* Hx = zu ? Hu : Hs;

    __shared__ unsigned short AsB[2][128 * 64];   // 32 KB
    __shared__ unsigned short Bb[2][64 * 64];     // 16 KB

    const int tid = threadIdx.x;
    const int lane = tid & 63;
    const int wave = tid >> 6;
    const int wm = wave >> 1;        // m-half (0,1)
    const int wn = wave & 1;         // n-half (0,1)

    f32x4 acc[4][2];
#pragma unroll
    for (int i = 0; i < 4; ++i)
#pragma unroll
        for (int j = 0; j < 2; ++j) acc[i][j] = (f32x4){0.f, 0.f, 0.f, 0.f};

    // A staging via dma (4 loads/thread/step)
    const int srow = tid >> 3;          // 0..31
    const int sc0 = tid & 7;
    const unsigned short* Aab = Abuf + (size_t)row0 * DIM;

    auto stageA = [&](int buf, int kt) {
#pragma unroll
        for (int i = 0; i < 4; ++i) {                          // 128 rows
            int row = i * 32 + srow;
            int csrc = sc0 ^ (row & 7);
            gload16(Aab + (size_t)row * DIM + kt + csrc * 8,
                    &AsB[buf][(i * 256 + tid) * 8]);
        }
    };

    // B: thread owns n-row bn = tid&63, chunks c = (tid>>6), (tid>>6)+4 (16 loads/step)
    const int bn = tid & 63;
    const int bc0 = tid >> 6;           // 0..3
    const float* Bgb = W + (size_t)e * DIM * HDIM + n0 + bn;

    float bl[2][8];
    auto bload = [&](int kt) {
#pragma unroll
        for (int cc = 0; cc < 2; ++cc) {
            int c = bc0 + cc * 4;
            const float* gs = Bgb + (size_t)(kt + c * 8) * HDIM;
#pragma unroll
            for (int jj = 0; jj < 8; ++jj)
                bl[cc][jj] = gs[(size_t)jj * HDIM];
        }
    };
    auto bwrite = [&](int buf) {
#pragma unroll
        for (int cc = 0; cc < 2; ++cc) {
            int c = bc0 + cc * 4;
            int la = bn * 64 + ((c ^ (bn & 7)) * 8);
            u32x4 v;
#pragma unroll
            for (int p = 0; p < 4; ++p)
                v[p] = f2bf2(bl[cc][2 * p], bl[cc][2 * p + 1]);
            *(u32x4*)&Bb[buf][la] = v;
        }
    };

    const int rsel = lane & 15;
    const int csrcf = lane >> 4;        // fragment k-chunk (0..3)

    stageA(0, 0);
    bload(0);
    bwrite(0);
    int cur = 0;
    for (int kt = 0; kt < DIM; kt += 64) {
        __syncthreads();                // buf[cur] ready
        const bool pre = (kt + 64 < DIM);
        if (pre) { stageA(cur ^ 1, kt + 64); bload(kt + 64); }   // issue early
        const unsigned short* Ac = AsB[cur];
        const unsigned short* Bc = Bb[cur];
#pragma unroll
        for (int kk = 0; kk < 2; ++kk) {
            bf16x8 af[4], bb[2];
#pragma unroll
            for (int i = 0; i < 4; ++i) {
                int ra = wm * 64 + i * 16 + rsel;
                af[i] = *(const bf16x8*)&Ac[ra * 64 + ((kk * 4 + csrcf) ^ (ra & 7)) * 8];
            }
#pragma unroll
            for (int j = 0; j < 2; ++j) {
                int rb = wn * 32 + j * 16 + rsel;
                bb[j] = *(const bf16x8*)&Bc[rb * 64 + ((kk * 4 + csrcf) ^ (rb & 7)) * 8];
            }
#pragma unroll
            for (int i = 0; i < 4; ++i)
#pragma unroll
                for (int j = 0; j < 2; ++j)
                    acc[i][j] = __builtin_amdgcn_mfma_f32_16x16x32_bf16(af[i], bb[j], acc[i][j], 0, 0, 0);
        }
        if (pre) bwrite(cur ^ 1);       // write late (loads covered by MFMAs)
        cur ^= 1;
    }

    const int c = lane & 15, rbase = (lane >> 4) * 4;
    const int obase = offsets[e];
#pragma unroll
    for (int i = 0; i < 4; ++i) {
#pragma unroll
        for (int r = 0; r < 4; ++r) {
            int lrow = mtile * 128 + wm * 64 + i * 16 + rbase + r;
            if (lrow < cnt) {
                size_t orow = (size_t)(obase + lrow);
#pragma unroll
                for (int j = 0; j < 2; ++j) {
                    float v = acc[i][j][r];
                    if (!zu) v = v / (1.f + __expf(-v));   // silu on gate path
                    Hx[orow * HDIM + n0 + wn * 32 + j * 16 + c] = f2bf(v);
                }
            }
        }
    }
}

// ---------------- GEMM2: y[tok] += w * ((Hs*Hu) @ Wd^T)
// (R18-proven internals.)  BM=128, BN=64, BK=64, acc[4][2], 48KB LDS -> 3/CU,
// K split x2. A staged in registers as the product silu(g)*u (write-late);
// B from fp32 dw. 1D grid, XCD-chunked, B-panel-major logical order:
// logical = n0idx*(TSLOTS*2) + slot*2 + kc.
__global__ __launch_bounds__(256, 3)
void gemm2_kernel(const unsigned short* __restrict__ Hs,
                  const unsigned short* __restrict__ Hu,
                  const float* __restrict__ dw,
                  float* __restrict__ y,
                  const int* __restrict__ offsets, const int* __restrict__ counts,
                  const int* __restrict__ row_tok, const float* __restrict__ row_w,
                  const int* __restrict__ tl_e, const int* __restrict__ tl_m) {
    const int log = xcd_logical(blockIdx.x, 16 * TSLOTS * 2);
    const int n0 = (log / (TSLOTS * 2)) * 64;
    const int rem = log % (TSLOTS * 2);
    const int slot = rem >> 1;
    const int kc = rem & 1;
    const int e = tl_e[slot];
    if (e < 0) return;
    const int mtile = tl_m[slot];
    const int cnt = counts[e];
    const int row0 = offsets[e] + mtile * 128;

    __shared__ unsigned short As[2][128 * 64];   // 32 KB
    __shared__ unsigned short Bs[2][64 * 64];    // 16 KB

    const int tid = threadIdx.x;
    const int lane = tid & 63;
    const int wave = tid >> 6;
    const int wm = wave >> 1, wn = wave & 1;

    f32x4 acc[4][2];
#pragma unroll
    for (int i = 0; i < 4; ++i)
#pragma unroll
        for (int j = 0; j < 2; ++j) acc[i][j] = (f32x4){0.f, 0.f, 0.f, 0.f};

    // A: reg-staged product Hs*Hu (8 loads/thread/step), swizzle applied on ds_write
    const int srow = tid >> 3;          // 0..31
    const int sc0 = tid & 7;
    const unsigned short* Asb = Hs + (size_t)row0 * HDIM;
    const unsigned short* Aub = Hu + (size_t)row0 * HDIM;

    u16x8 as_[4], au_[4];
    auto aload = [&](int kt) {
#pragma unroll
        for (int i = 0; i < 4; ++i) {
            int row = i * 32 + srow;
            size_t go = (size_t)row * HDIM + kt + sc0 * 8;   // natural chunk (coalesced)
            as_[i] = *(const u16x8*)&Asb[go];
            au_[i] = *(const u16x8*)&Aub[go];
        }
    };
    auto awrite = [&](int buf) {
#pragma unroll
        for (int i = 0; i < 4; ++i) {
            int row = i * 32 + srow;
            int la = row * 64 + ((sc0 ^ (row & 7)) * 8);     // swizzled LDS dest
            u32x4 v;
#pragma unroll
            for (int p = 0; p < 4; ++p) {
                float h0 = bf2f(as_[i][2 * p])     * bf2f(au_[i][2 * p]);
                float h1 = bf2f(as_[i][2 * p + 1]) * bf2f(au_[i][2 * p + 1]);
                v[p] = f2bf2(h0, h1);
            }
            *(u32x4*)&As[buf][la] = v;
        }
    };

    // B: thread owns n-row bn = tid&63, chunks c = (tid>>6), (tid>>6)+4 (16 loads/step)
    const int bn = tid & 63;
    const int bc0 = tid >> 6;
    const float* Bbb = dw + (size_t)e * HDIM * DIM + n0 + bn;

    float bl[2][8];
    auto bload = [&](int kt) {
#pragma unroll
        for (int cc = 0; cc < 2; ++cc) {
            int c = bc0 + cc * 4;
            const float* bs = Bbb + (size_t)(kt + c * 8) * DIM;
#pragma unroll
            for (int jj = 0; jj < 8; ++jj)
                bl[cc][jj] = bs[(size_t)jj * DIM];
        }
    };
    auto bwrite = [&](int buf) {
#pragma unroll
        for (int cc = 0; cc < 2; ++cc) {
            int c = bc0 + cc * 4;
            int la = bn * 64 + ((c ^ (bn & 7)) * 8);
            u32x4 v;
#pragma unroll
            for (int p = 0; p < 4; ++p)
                v[p] = f2bf2(bl[cc][2 * p], bl[cc][2 * p + 1]);
            *(u32x4*)&Bs[buf][la] = v;
        }
    };

    const int rsel = lane & 15;
    const int csrcf = lane >> 4;

    const int kbeg = kc * (HDIM / 2);
    const int kend = kbeg + (HDIM / 2);

    aload(kbeg);
    bload(kbeg);
    awrite(0);
    bwrite(0);
    int cur = 0;
    for (int kt = kbeg; kt < kend; kt += 64) {
        __syncthreads();
        const bool pre = (kt + 64 < kend);
        if (pre) { aload(kt + 64); bload(kt + 64); }     // issue early
        const unsigned short* Ac = As[cur];
        const unsigned short* Bc = Bs[cur];
#pragma unroll
        for (int kk = 0; kk < 2; ++kk) {
            bf16x8 af[4], bf[2];
#pragma unroll
            for (int i = 0; i < 4; ++i) {
                int ra = wm * 64 + i * 16 + rsel;
                af[i] = *(const bf16x8*)&Ac[ra * 64 + ((kk * 4 + csrcf) ^ (ra & 7)) * 8];
            }
#pragma unroll
            for (int j = 0; j < 2; ++j) {
                int rb = wn * 32 + j * 16 + rsel;
                bf[j] = *(const bf16x8*)&Bc[rb * 64 + ((kk * 4 + csrcf) ^ (rb & 7)) * 8];
            }
#pragma unroll
            for (int i = 0; i < 4; ++i)
#pragma unroll
                for (int j = 0; j < 2; ++j)
                    acc[i][j] = __builtin_amdgcn_mfma_f32_16x16x32_bf16(af[i], bf[j], acc[i][j], 0, 0, 0);
        }
        if (pre) { awrite(cur ^ 1); bwrite(cur ^ 1); }   // write late
        cur ^= 1;
    }

    const int c = lane & 15, rbase = (lane >> 4) * 4;
    const int obase = offsets[e];
#pragma unroll
    for (int i = 0; i < 4; ++i) {
#pragma unroll
        for (int r = 0; r < 4; ++r) {
            int lrow = mtile * 128 + wm * 64 + i * 16 + rbase + r;
            if (lrow < cnt) {
                int grow = obase + lrow;
                int tok = row_tok[grow];
                float w = row_w[grow];
#pragma unroll
                for (int j = 0; j < 2; ++j) {
                    atomicAdd(&y[(size_t)tok * DIM + n0 + wn * 32 + j * 16 + c], w * acc[i][j][r]);
                }
            }
        }
    }
}

extern "C" void kernel_launch(void* const* d_in, const int* in_sizes, int n_in,
                              void* d_out, int out_size, void* d_ws, size_t ws_size,
                              hipStream_t stream) {
    const float* x  = (const float*)d_in[0];
    const float* rw = (const float*)d_in[1];
    const float* gw = (const float*)d_in[2];
    const float* uw = (const float*)d_in[3];
    const float* dw = (const float*)d_in[4];
    float* y = (float*)d_out;

    char* ws = (char*)d_ws;
    int*   counts  = (int*)(ws + 0);
    int*   cursors = (int*)(ws + 32);
    int*   offsets = (int*)(ws + 64);
    int*   top_idx = (int*)(ws + 128);
    float* top_w   = (float*)(ws + 128 + 16384);
    int*   row_tok = (int*)(ws + 128 + 32768);
    float* row_w   = (float*)(ws + 128 + 32768 + 16896);
    int*   tl_e    = (int*)(ws + 128 + 32768 + 2 * 16896);
    int*   tl_m    = (int*)(ws + 128 + 32768 + 2 * 16896 + 512);
    size_t off = 128 + 32768 + 2 * 16896 + 1024;
    off = (off + 255) & ~(size_t)255;
    unsigned short* Abuf = (unsigned short*)(ws + off); off += (size_t)ROWS_PAD * DIM * 2;
    unsigned short* Hs   = (unsigned short*)(ws + off); off += (size_t)ROWS_PAD * HDIM * 2;
    unsigned short* Hu   = (unsigned short*)(ws + off); off += (size_t)ROWS_PAD * HDIM * 2;
    if (ws_size < off) return;  // workspace too small: fail loudly (zero output)

    hipMemsetAsync(counts, 0, 32, stream);
    hipMemsetAsync(d_out, 0, (size_t)out_size * 4, stream);

    router_kernel<<<T_TOK / 4, 256, 0, stream>>>(x, rw, counts, top_idx, top_w);
    scan_kernel<<<1, 64, 0, stream>>>(counts, offsets, cursors, tl_e, tl_m);
    gather_kernel<<<T_TOK, 256, 0, stream>>>(x, top_idx, top_w, cursors, row_tok, row_w, Abuf);

    gemm1s_kernel<<<64 * TSLOTS, 256, 0, stream>>>(Abuf, gw, uw, Hs, Hu,
                                                   offsets, counts, tl_e, tl_m);
    gemm2_kernel<<<16 * TSLOTS * 2, 256, 0, stream>>>(Hs, Hu, dw, y, offsets, counts,
                                                      row_tok, row_w, tl_e, tl_m);
}

// Round 23
// 246.365 us; speedup vs baseline: 1.3245x; 1.2021x over previous
//
#include <hip/hip_runtime.h>
#include <hip/hip_bf16.h>
#include <stdint.h>

#define T_TOK 2048
#define DIM   1024
#define HDIM  2048
#define NE    8
#define ROWS_PAD 4224   // 4096 routed rows + 128 pad for tile overrun
#define TSLOTS 40       // max live (expert,mtile) pairs: 32 + 7 = 39

typedef __attribute__((ext_vector_type(8))) short bf16x8;
typedef __attribute__((ext_vector_type(8))) unsigned short u16x8;
typedef __attribute__((ext_vector_type(4))) float f32x4;
typedef __attribute__((ext_vector_type(4))) unsigned int u32x4;

// hardware RNE converts (compiler emits v_cvt_pk_bf16_f32 / single cvt)
__device__ __forceinline__ unsigned short f2bf(float f) {
    union { __hip_bfloat16 h; unsigned short u; } cv;
    cv.h = __float2bfloat16(f);
    return cv.u;
}
__device__ __forceinline__ unsigned int f2bf2(float lo, float hi) {
    union { __hip_bfloat162 h; unsigned int u; } cv;
    cv.h = __float22bfloat162_rn(make_float2(lo, hi));
    return cv.u;
}
__device__ __forceinline__ float bf2f(unsigned short b) {
    union { unsigned int u; float f; } v; v.u = ((unsigned int)b) << 16;
    return v.f;
}

__device__ __forceinline__ void gload16(const void* g, void* l) {
    __builtin_amdgcn_global_load_lds(
        (const __attribute__((address_space(1))) void*)g,
        (__attribute__((address_space(3))) void*)l, 16, 0, 0);
}

// ---------------- router: logits = x @ rw, top-2 softmax, counts
__global__ void router_kernel(const float* __restrict__ x, const float* __restrict__ rw,
                              int* __restrict__ counts, int* __restrict__ top_idx,
                              float* __restrict__ top_w) {
    int wid = (blockIdx.x * blockDim.x + threadIdx.x) >> 6;
    int lane = threadIdx.x & 63;
    if (wid >= T_TOK) return;
    float acc[NE];
#pragma unroll
    for (int e = 0; e < NE; ++e) acc[e] = 0.f;
    const float* xr = x + (size_t)wid * DIM;
    for (int i = lane; i < DIM; i += 64) {
        float xv = xr[i];
        const float* wr = rw + (size_t)i * NE;
#pragma unroll
        for (int e = 0; e < NE; ++e) acc[e] += xv * wr[e];
    }
#pragma unroll
    for (int off = 32; off; off >>= 1) {
#pragma unroll
        for (int e = 0; e < NE; ++e) acc[e] += __shfl_xor(acc[e], off, 64);
    }
    if (lane == 0) {
        float v0 = -1e30f, v1 = -1e30f; int i0 = 0, i1 = 0;
#pragma unroll
        for (int e = 0; e < NE; ++e) {
            float v = acc[e];
            if (v > v0) { v1 = v0; i1 = i0; v0 = v; i0 = e; }
            else if (v > v1) { v1 = v; i1 = e; }
        }
        float e1 = __expf(v1 - v0);
        float s = 1.f + e1;
        top_idx[wid * 2]     = i0;
        top_idx[wid * 2 + 1] = i1;
        top_w[wid * 2]     = 1.f / s;
        top_w[wid * 2 + 1] = e1 / s;
        atomicAdd(&counts[i0], 1);
        atomicAdd(&counts[i1], 1);
    }
}

// ---------------- scan + compact tile list (holes only at the tail)
__global__ void scan_kernel(const int* __restrict__ counts, int* __restrict__ offsets,
                            int* __restrict__ cursors,
                            int* __restrict__ tl_e, int* __restrict__ tl_m) {
    if (threadIdx.x == 0) {
        int run = 0;
        for (int e = 0; e < NE; ++e) { offsets[e] = run; cursors[e] = run; run += counts[e]; }
        int n = 0;
        for (int e = 0; e < NE; ++e) {
            int mt = (counts[e] + 127) >> 7;
            for (int m = 0; m < mt && n < 64; ++m) { tl_e[n] = e; tl_m[n] = m; ++n; }
        }
        for (; n < 64; ++n) tl_e[n] = -1;
    }
}

// ---------------- gather: pack each token's row (bf16) into its 2 experts' segments
__global__ void gather_kernel(const float* __restrict__ x, const int* __restrict__ top_idx,
                              const float* __restrict__ top_w, int* __restrict__ cursors,
                              int* __restrict__ row_tok, float* __restrict__ row_w,
                              unsigned short* __restrict__ Abuf) {
    int t = blockIdx.x;
    __shared__ int pos[2];
    if (threadIdx.x < 2) {
        int k = threadIdx.x;
        int e = top_idx[t * 2 + k];
        int p = atomicAdd(&cursors[e], 1);
        pos[k] = p;
        row_tok[p] = t;
        row_w[p] = top_w[t * 2 + k];
    }
    __syncthreads();
    const float4* xr = (const float4*)(x + (size_t)t * DIM);
    float4 v = xr[threadIdx.x];
    unsigned int lo = f2bf2(v.x, v.y), hi = f2bf2(v.z, v.w);
    uint2 b; b.x = lo; b.y = hi;
    uint2* A4 = (uint2*)Abuf;
    A4[(size_t)pos[0] * (DIM / 4) + threadIdx.x] = b;
    A4[(size_t)pos[1] * (DIM / 4) + threadIdx.x] = b;
}

// ---------------- GEMM1: hidden = silu(A @ Wg^T) * (A @ Wu^T), per expert
// BM=128, BN=64, BK=64; 4 waves = 2(m) x 2(gate|up); 64KB LDS double-buffered.
// B staged directly from fp32 gw/uw (depth-1 reg prefetch, write-late),
// converted with v_cvt_pk_bf16_f32. A via global_load_lds.  (R12 schedule.)
__global__ __launch_bounds__(256, 2)
void gemm1_kernel(const unsigned short* __restrict__ Abuf,
                  const float* __restrict__ gw,
                  const float* __restrict__ uw,
                  unsigned short* __restrict__ Hbuf,
                  const int* __restrict__ offsets, const int* __restrict__ counts,
                  const int* __restrict__ tl_e, const int* __restrict__ tl_m) {
    const int slot = blockIdx.y;
    const int e = tl_e[slot];
    if (e < 0) return;
    const int mtile = tl_m[slot];
    const int cnt = counts[e];
    const int n0 = blockIdx.x * 64;
    const int row0 = offsets[e] + mtile * 128;

    __shared__ __align__(16) unsigned char lds_raw[65536];
    unsigned short* AsB = (unsigned short*)lds_raw;            // [2][128*64] = 32KB
    unsigned short* BgB = (unsigned short*)(lds_raw + 32768);  // [2][64*64]  = 16KB
    unsigned short* BuB = (unsigned short*)(lds_raw + 49152);  // [2][64*64]  = 16KB
    unsigned short* ex  = (unsigned short*)lds_raw;            // epilogue [2][64][64] bf16 (aliases AsB)

    const int tid = threadIdx.x;
    const int lane = tid & 63;
    const int wave = tid >> 6;
    const int wm = wave >> 1;        // m-half (0,1)
    const int wu = wave & 1;         // 0 = gate, 1 = up

    f32x4 acc[4][2];
    f32x4 acc2[4][2];
#pragma unroll
    for (int i = 0; i < 4; ++i)
#pragma unroll
        for (int j = 0; j < 2; ++j) {
            acc[i][j] = (f32x4){0.f, 0.f, 0.f, 0.f};
            acc2[i][j] = (f32x4){0.f, 0.f, 0.f, 0.f};
        }

    // A staging via dma (4 loads/thread/step)
    const int srow = tid >> 3;          // 0..31
    const int sc0 = tid & 7;
    const unsigned short* Aab = Abuf + (size_t)row0 * DIM;

    auto stageA = [&](int buf, int kt) {
#pragma unroll
        for (int i = 0; i < 4; ++i) {                          // 128 rows
            int row = i * 32 + srow;
            int csrc = sc0 ^ (row & 7);
            gload16(Aab + (size_t)row * DIM + kt + csrc * 8,
                    AsB + buf * 8192 + (i * 256 + tid) * 8);
        }
    };

    // B: thread owns n = tid&63, chunks c = (tid>>6), (tid>>6)+4 (32 loads/step)
    const int bn = tid & 63;
    const int bc0 = tid >> 6;           // 0..3
    const float* Bgb = gw + (size_t)e * DIM * HDIM + n0 + bn;
    const float* Bub = uw + (size_t)e * DIM * HDIM + n0 + bn;

    float bgl[2][8], bul[2][8];
    auto bload = [&](int kt) {
#pragma unroll
        for (int cc = 0; cc < 2; ++cc) {
            int c = bc0 + cc * 4;
            const float* gs = Bgb + (size_t)(kt + c * 8) * HDIM;
            const float* us = Bub + (size_t)(kt + c * 8) * HDIM;
#pragma unroll
            for (int jj = 0; jj < 8; ++jj) {
                bgl[cc][jj] = gs[(size_t)jj * HDIM];
                bul[cc][jj] = us[(size_t)jj * HDIM];
            }
        }
    };
    auto bwrite = [&](int buf) {
#pragma unroll
        for (int cc = 0; cc < 2; ++cc) {
            int c = bc0 + cc * 4;
            int la = bn * 64 + ((c ^ (bn & 7)) * 8);
            u32x4 vg, vu;
#pragma unroll
            for (int p = 0; p < 4; ++p) {
                vg[p] = f2bf2(bgl[cc][2 * p], bgl[cc][2 * p + 1]);
                vu[p] = f2bf2(bul[cc][2 * p], bul[cc][2 * p + 1]);
            }
            *(u32x4*)&BgB[buf * 4096 + la] = vg;
            *(u32x4*)&BuB[buf * 4096 + la] = vu;
        }
    };

    const int rsel = lane & 15;
    const int csrcf = lane >> 4;        // fragment k-chunk (0..3)

    stageA(0, 0);
    bload(0);
    bwrite(0);
    int cur = 0;
    for (int kt = 0; kt < DIM; kt += 64) {
        __syncthreads();                // buf[cur] ready
        const bool pre = (kt + 64 < DIM);
        if (pre) { stageA(cur ^ 1, kt + 64); bload(kt + 64); }   // issue early
        const unsigned short* Ac = AsB + cur * 8192;
        const unsigned short* Bc = (wu ? BuB : BgB) + cur * 4096;
#pragma unroll
        for (int kk = 0; kk < 2; ++kk) {
            bf16x8 af[4], bb[4];
#pragma unroll
            for (int i = 0; i < 4; ++i) {
                int ra = wm * 64 + i * 16 + rsel;
                af[i] = *(const bf16x8*)&Ac[ra * 64 + ((kk * 4 + csrcf) ^ (ra & 7)) * 8];
                int rb = i * 16 + rsel;
                bb[i] = *(const bf16x8*)&Bc[rb * 64 + ((kk * 4 + csrcf) ^ (rb & 7)) * 8];
            }
#pragma unroll
            for (int i = 0; i < 4; ++i) {
                acc[i][0]  = __builtin_amdgcn_mfma_f32_16x16x32_bf16(af[i], bb[0], acc[i][0], 0, 0, 0);
                acc[i][1]  = __builtin_amdgcn_mfma_f32_16x16x32_bf16(af[i], bb[1], acc[i][1], 0, 0, 0);
                acc2[i][0] = __builtin_amdgcn_mfma_f32_16x16x32_bf16(af[i], bb[2], acc2[i][0], 0, 0, 0);
                acc2[i][1] = __builtin_amdgcn_mfma_f32_16x16x32_bf16(af[i], bb[3], acc2[i][1], 0, 0, 0);
            }
        }
        if (pre) bwrite(cur ^ 1);       // write late (loads covered by MFMAs)
        cur ^= 1;
    }

    // ---- epilogue: up-waves export u (bf16) via LDS; gate-waves apply silu(g)*u
    const int c = lane & 15, rbase = (lane >> 4) * 4;
    const int obase = offsets[e];
    __syncthreads();                    // all staging reads done; safe to alias LDS
    if (wu) {
#pragma unroll
        for (int i = 0; i < 4; ++i)
#pragma unroll
            for (int r = 0; r < 4; ++r) {
                int row64 = i * 16 + rbase + r;
                ex[wm * 4096 + row64 * 64 + 0 * 16 + c]  = f2bf(acc[i][0][r]);
                ex[wm * 4096 + row64 * 64 + 1 * 16 + c]  = f2bf(acc[i][1][r]);
                ex[wm * 4096 + row64 * 64 + 2 * 16 + c]  = f2bf(acc2[i][0][r]);
                ex[wm * 4096 + row64 * 64 + 3 * 16 + c]  = f2bf(acc2[i][1][r]);
            }
    }
    __syncthreads();
    if (!wu) {
#pragma unroll
        for (int i = 0; i < 4; ++i) {
#pragma unroll
            for (int r = 0; r < 4; ++r) {
                int row64 = i * 16 + rbase + r;
                int lrow = mtile * 128 + wm * 64 + row64;
                if (lrow < cnt) {
                    size_t orow = (size_t)(obase + lrow);
                    float gv[4] = {acc[i][0][r], acc[i][1][r], acc2[i][0][r], acc2[i][1][r]};
#pragma unroll
                    for (int j = 0; j < 4; ++j) {
                        float g = gv[j];
                        float u = bf2f(ex[wm * 4096 + row64 * 64 + j * 16 + c]);
                        float h = g * u / (1.f + __expf(-g));
                        Hbuf[orow * HDIM + n0 + j * 16 + c] = f2bf(h);
                    }
                }
            }
        }
    }
}

// ---------------- GEMM2: y[tok] += w * (hidden @ Wd^T)
// BM=128, BN=128, BK=64, K split x2. B staged directly from fp32 dw with
// v_cvt_pk converts. A (Hbuf) via global_load_lds.  (R16-proven.)
__global__ __launch_bounds__(256, 2)
void gemm2_kernel(const unsigned short* __restrict__ Hbuf,
                  const float* __restrict__ dw,
                  float* __restrict__ y,
                  const int* __restrict__ offsets, const int* __restrict__ counts,
                  const int* __restrict__ row_tok, const float* __restrict__ row_w,
                  const int* __restrict__ tl_e, const int* __restrict__ tl_m) {
    const int slot = blockIdx.y;
    const int e = tl_e[slot];
    if (e < 0) return;
    const int mtile = tl_m[slot];
    const int kc = blockIdx.z;
    const int cnt = counts[e];
    const int n0 = blockIdx.x * 128;
    const int row0 = offsets[e] + mtile * 128;

    __shared__ unsigned short As[2][128 * 64];   // 32 KB
    __shared__ unsigned short Bs[2][128 * 64];   // 32 KB

    const int tid = threadIdx.x;
    const int lane = tid & 63;
    const int wave = tid >> 6;
    const int wm = wave >> 1, wn = wave & 1;

    f32x4 acc[4][4];
#pragma unroll
    for (int i = 0; i < 4; ++i)
#pragma unroll
        for (int j = 0; j < 4; ++j) acc[i][j] = (f32x4){0.f, 0.f, 0.f, 0.f};

    const int srow0 = tid >> 3;
    const int sc0 = tid & 7;
    const unsigned short* Aab = Hbuf + (size_t)row0 * HDIM;

    auto stageA = [&](int buf, int kt) {
#pragma unroll
        for (int i = 0; i < 4; ++i) {
            int row = i * 32 + srow0;
            int csrc = sc0 ^ (row & 7);
            gload16(Aab + (size_t)row * HDIM + kt + csrc * 8,
                    &As[buf][(i * 256 + tid) * 8]);
        }
    };

    // B: thread owns n = tid&127, chunks c = (tid>>7)*4 + 0..3 (32 loads/step)
    const int bn = tid & 127;
    const int bc0 = (tid >> 7) * 4;     // 0 or 4
    const float* Bbb = dw + (size_t)e * HDIM * DIM + n0 + bn;

    float bl[4][8];
    auto bload = [&](int kt) {
#pragma unroll
        for (int cc = 0; cc < 4; ++cc) {
            const float* bs = Bbb + (size_t)(kt + (bc0 + cc) * 8) * DIM;
#pragma unroll
            for (int jj = 0; jj < 8; ++jj)
                bl[cc][jj] = bs[(size_t)jj * DIM];
        }
    };
    auto bwrite = [&](int buf) {
#pragma unroll
        for (int cc = 0; cc < 4; ++cc) {
            int c = bc0 + cc;
            int la = bn * 64 + ((c ^ (bn & 7)) * 8);
            u32x4 v;
#pragma unroll
            for (int p = 0; p < 4; ++p)
                v[p] = f2bf2(bl[cc][2 * p], bl[cc][2 * p + 1]);
            *(u32x4*)&Bs[buf][la] = v;
        }
    };

    const int rsel = lane & 15;
    const int csrcf = lane >> 4;

    const int kbeg = kc * (HDIM / 2);
    const int kend = kbeg + (HDIM / 2);

    stageA(0, kbeg);
    bload(kbeg);
    bwrite(0);
    int cur = 0;
    for (int kt = kbeg; kt < kend; kt += 64) {
        __syncthreads();
        const bool pre = (kt + 64 < kend);
        if (pre) { stageA(cur ^ 1, kt + 64); bload(kt + 64); }
        const unsigned short* Ac = As[cur];
        const unsigned short* Bc = Bs[cur];
#pragma unroll
        for (int kk = 0; kk < 2; ++kk) {
            bf16x8 af[4], bf[4];
#pragma unroll
            for (int i = 0; i < 4; ++i) {
                int ra = wm * 64 + i * 16 + rsel;
                af[i] = *(const bf16x8*)&Ac[ra * 64 + ((kk * 4 + csrcf) ^ (ra & 7)) * 8];
                int rb = wn * 64 + i * 16 + rsel;
                bf[i] = *(const bf16x8*)&Bc[rb * 64 + ((kk * 4 + csrcf) ^ (rb & 7)) * 8];
            }
#pragma unroll
            for (int i = 0; i < 4; ++i)
#pragma unroll
                for (int j = 0; j < 4; ++j)
                    acc[i][j] = __builtin_amdgcn_mfma_f32_16x16x32_bf16(af[i], bf[j], acc[i][j], 0, 0, 0);
        }
        if (pre) bwrite(cur ^ 1);
        cur ^= 1;
    }

    const int c = lane & 15, rbase = (lane >> 4) * 4;
    const int obase = offsets[e];
#pragma unroll
    for (int i = 0; i < 4; ++i) {
#pragma unroll
        for (int r = 0; r < 4; ++r) {
            int lrow = mtile * 128 + wm * 64 + i * 16 + rbase + r;
            if (lrow < cnt) {
                int grow = obase + lrow;
                int tok = row_tok[grow];
                float w = row_w[grow];
#pragma unroll
                for (int j = 0; j < 4; ++j) {
                    atomicAdd(&y[(size_t)tok * DIM + n0 + wn * 64 + j * 16 + c], w * acc[i][j][r]);
                }
            }
        }
    }
}

extern "C" void kernel_launch(void* const* d_in, const int* in_sizes, int n_in,
                              void* d_out, int out_size, void* d_ws, size_t ws_size,
                              hipStream_t stream) {
    const float* x  = (const float*)d_in[0];
    const float* rw = (const float*)d_in[1];
    const float* gw = (const float*)d_in[2];
    const float* uw = (const float*)d_in[3];
    const float* dw = (const float*)d_in[4];
    float* y = (float*)d_out;

    char* ws = (char*)d_ws;
    int*   counts  = (int*)(ws + 0);
    int*   cursors = (int*)(ws + 32);
    int*   offsets = (int*)(ws + 64);
    int*   top_idx = (int*)(ws + 128);
    float* top_w   = (float*)(ws + 128 + 16384);
    int*   row_tok = (int*)(ws + 128 + 32768);
    float* row_w   = (float*)(ws + 128 + 32768 + 16896);
    int*   tl_e    = (int*)(ws + 128 + 32768 + 2 * 16896);
    int*   tl_m    = (int*)(ws + 128 + 32768 + 2 * 16896 + 256);
    size_t off = 128 + 32768 + 2 * 16896 + 512;
    off = (off + 255) & ~(size_t)255;
    unsigned short* Abuf = (unsigned short*)(ws + off); off += (size_t)ROWS_PAD * DIM * 2;
    unsigned short* Hbuf = (unsigned short*)(ws + off); off += (size_t)ROWS_PAD * HDIM * 2;
    if (ws_size < off) return;  // workspace too small: fail loudly (zero output)

    hipMemsetAsync(counts, 0, 32, stream);
    hipMemsetAsync(d_out, 0, (size_t)out_size * 4, stream);

    router_kernel<<<T_TOK / 4, 256, 0, stream>>>(x, rw, counts, top_idx, top_w);
    scan_kernel<<<1, 64, 0, stream>>>(counts, offsets, cursors, tl_e, tl_m);
    gather_kernel<<<T_TOK, 256, 0, stream>>>(x, top_idx, top_w, cursors, row_tok, row_w, Abuf);

    gemm1_kernel<<<dim3(HDIM / 64, TSLOTS), 256, 0, stream>>>(Abuf, gw, uw, Hbuf,
                                                              offsets, counts, tl_e, tl_m);
    gemm2_kernel<<<dim3(DIM / 128, TSLOTS, 2), 256, 0, stream>>>(Hbuf, dw, y, offsets, counts,
                                                                 row_tok, row_w, tl_e, tl_m);
}